// Round 9
// baseline (519.758 us; speedup 1.0000x reference)
//
#include <hip/hip_runtime.h>

typedef _Float16 f16;
typedef _Float16 f16x4 __attribute__((ext_vector_type(4)));
typedef _Float16 f16x8 __attribute__((ext_vector_type(8)));
typedef float f32x4  __attribute__((ext_vector_type(4)));

#define MFMAH(a, b, c)   __builtin_amdgcn_mfma_f32_16x16x32_f16(a, b, c, 0, 0, 0)
#define MFMAH16(a, b, c) __builtin_amdgcn_mfma_f32_16x16x16f16(a, b, c, 0, 0, 0)

constexpr int D = 256;
constexpr int S = 4096;
constexpr int BATCH = 4;
constexpr int NROWS = BATCH * S;           // 16384
constexpr float SCALE = 0.0625f;           // 1/sqrt(256)
constexpr size_t NE = (size_t)NROWS * D;   // 4.19M elems

// async global->LDS: per-lane src addr, wave-uniform LDS base (+lane*16 by HW)
__device__ __forceinline__ void gll16(const void* g, void* l) {
  __builtin_amdgcn_global_load_lds(
      (const __attribute__((address_space(1))) unsigned int*)g,
      (__attribute__((address_space(3))) unsigned int*)l, 16, 0, 0);
}

// ---------------------------------------------------------------------------
// Prep: Wt[m][n][k] = w_m[k][n] fp16. Write-coalesced.
// ---------------------------------------------------------------------------
__global__ __launch_bounds__(256)
void prep_wt_kernel(const float* __restrict__ wq, const float* __restrict__ wk,
                    const float* __restrict__ wv, const float* __restrict__ wo,
                    f16* __restrict__ Wt)
{
  const int m = blockIdx.y;
  const float* w = (m == 0) ? wq : (m == 1) ? wk : (m == 2) ? wv : wo;
  int id = blockIdx.x * 256 + threadIdx.x;    // 0..65535
  int n = id >> 8, k = id & 255;
  Wt[((size_t)m << 16) + n * 256 + k] = (f16)w[k * 256 + n];
}

// ---------------------------------------------------------------------------
// QKV projection via MFMA with LDS-staged B tiles (dbuf, gll16).
// Q: row-major fp16 scaled by SCALE.
// Kf: 16-key frag groups (g=key>>4): 8 frags of 1KB, frag kc = dims
//     [kc*32,kc*32+32) as [dc:4][key:16][d8:8]   (r6-validated)
// Vf (NEW, 16-key groups): 8 frags of 1KB; frag f = cts {2f,2f+1}; per ct
//     512B = [quadk:4][dim16:16][key4:4] f16 — lane-linear b64 for PV 16x16x16.
// ---------------------------------------------------------------------------
__global__ __launch_bounds__(256)
void qkv_mfma_kernel(const float* __restrict__ in, const f16* __restrict__ Wt,
                     const float* __restrict__ bq, const float* __restrict__ bk,
                     const float* __restrict__ bv,
                     f16* __restrict__ Qh, f16* __restrict__ Kf, f16* __restrict__ Vf)
{
  __shared__ __align__(16) char smem[32768];   // B dbuf (2x16KB); reused by epilogue
  const int m = blockIdx.y;
  const int tid = threadIdx.x, lane = tid & 63, w = tid >> 6;
  const int l15 = lane & 15, quad = lane >> 4;
  const int row0 = blockIdx.x * 64 + w * 16;
  const f16* Wm = Wt + ((size_t)m << 16);
  const float* bias = (m == 0) ? bq : (m == 1) ? bk : bv;

  // A fragments: 16 rows of `in`, fp32 -> fp16 up front
  f16x8 af[8];
  {
    const float* arow = in + (size_t)(row0 + l15) * 768 + m * 256 + quad * 8;
#pragma unroll
    for (int kc = 0; kc < 8; ++kc) {
      float4 a0 = *(const float4*)(arow + kc * 32);
      float4 a1 = *(const float4*)(arow + kc * 32 + 4);
      f16x8 a;
      a[0] = (f16)a0.x; a[1] = (f16)a0.y; a[2] = (f16)a0.z; a[3] = (f16)a0.w;
      a[4] = (f16)a1.x; a[5] = (f16)a1.y; a[6] = (f16)a1.z; a[7] = (f16)a1.w;
      af[kc] = a;
    }
  }

  auto stageB = [&](int buf, int kc) {
    char* base = smem + buf * 16384;
#pragma unroll
    for (int i = 0; i < 4; ++i) {
      int ct = 4 * w + i;
      gll16(Wm + (ct * 16 + l15) * 256 + kc * 32 + quad * 8,
            base + ct * 1024 + lane * 16);
    }
  };

  f32x4 acc[16];
#pragma unroll
  for (int ct = 0; ct < 16; ++ct) acc[ct] = (f32x4){0.f, 0.f, 0.f, 0.f};

  stageB(0, 0);
  for (int kc = 0; kc < 8; ++kc) {
    __syncthreads();
    if (kc < 7) stageB((kc + 1) & 1, kc + 1);
    const char* Bb = smem + (kc & 1) * 16384;
#pragma unroll
    for (int ct = 0; ct < 16; ++ct) {
      f16x8 b = *(const f16x8*)(Bb + ct * 1024 + lane * 16);
      acc[ct] = MFMAH(af[kc], b, acc[ct]);
    }
  }
  __syncthreads();                         // B buffers dead; reuse for epilogue

  const int b_ = row0 >> 12;

  if (m == 0) {
    f16* ws = (f16*)(smem + w * 8192);
#pragma unroll
    for (int ct = 0; ct < 16; ++ct) {
      float bct = bias[ct * 16 + l15];
#pragma unroll
      for (int r = 0; r < 4; ++r)
        ws[(quad * 4 + r) * 256 + ct * 16 + l15] = (f16)((acc[ct][r] + bct) * SCALE);
    }
    f16* dst = Qh + (size_t)row0 * 256;
#pragma unroll
    for (int i = 0; i < 8; ++i)
      *(uint4*)(dst + lane * 8 + i * 512) = *(const uint4*)(ws + lane * 8 + i * 512);
  } else if (m == 1) {
    f16* ws = (f16*)(smem + w * 8192);
#pragma unroll
    for (int ct = 0; ct < 16; ++ct) {
      float bct = bias[ct * 16 + l15];
      int base = (ct >> 1) * 512 + ((ct & 1) * 2 + (l15 >> 3)) * 128 + (l15 & 7);
#pragma unroll
      for (int r = 0; r < 4; ++r)
        ws[base + (quad * 4 + r) * 8] = (f16)(acc[ct][r] + bct);
    }
    const int g = (row0 & 4095) >> 4;
    f16* dst = Kf + ((size_t)(b_ * 256 + g)) * 4096;
#pragma unroll
    for (int i = 0; i < 8; ++i)
      *(uint4*)(dst + lane * 8 + i * 512) = *(const uint4*)(ws + lane * 8 + i * 512);
  } else {
    // V: wave-local 16-key frag image (8KB = 8 frags), then coalesced dump.
    // element (key=quad*4+r, dim=ct*16+l15) ->
    //   f16 idx = (ct>>1)*512 + (ct&1)*256 + quad*64 + l15*4 + r
    f16* ws = (f16*)(smem + w * 8192);
#pragma unroll
    for (int ct = 0; ct < 16; ++ct) {
      float bct = bias[ct * 16 + l15];
      int idx = (ct >> 1) * 512 + (ct & 1) * 256 + quad * 64 + l15 * 4;
      f16x4 hv;
#pragma unroll
      for (int r = 0; r < 4; ++r) hv[r] = (f16)(acc[ct][r] + bct);
      *(f16x4*)&ws[idx] = hv;
    }
    const int gv = (row0 & 4095) >> 4;
    f16* dst = Vf + (size_t)(b_ * 256 + gv) * 4096;
#pragma unroll
    for (int i = 0; i < 8; ++i)
      *(uint4*)(dst + lane * 8 + i * 512) = *(const uint4*)(ws + lane * 8 + i * 512);
  }
}

// ---------------------------------------------------------------------------
// fp16 MFMA flash attention v9. 1024 blocks x 128 thr (2 waves, Tq=32/wave),
// LDS 2x16KB => ~5 blocks/CU (5 independent barrier domains, ~10 waves/CU).
// combo = bx&15 -> (b=combo&3, kz=combo>>2); qb = bx>>4 in [0,64).
// Split-K=4, 16-key tiles, 64 iters. QK: 16x16x32 (K frags unchanged).
// PV: 16x16x16f16 over 16 keys (pah f16x4 + Vf b64 frags).
// ---------------------------------------------------------------------------
__global__ __launch_bounds__(128, 3)
void attn9_kernel(const f16* __restrict__ Qh, const char* __restrict__ Kf,
                  const char* __restrict__ Vf,
                  f16* __restrict__ Pp, float* __restrict__ Mp, float* __restrict__ Lp)
{
  __shared__ __align__(16) char KVs[2][16384];   // [K 8 frags][V 8 frags]

  const int tid = threadIdx.x, lane = tid & 63, w = tid >> 6;   // w: 0..1
  const int l15 = lane & 15, quad = lane >> 4;

  const int bx    = blockIdx.x;
  const int combo = bx & 15;
  const int b     = combo & 3;
  const int kz    = combo >> 2;
  const int qb    = bx >> 4;                   // 0..63
  const int qrow0 = qb * 64 + w * 32;
  const int grow  = b * 4096 + qrow0;

  // resident Q B-fragments (n=q=l15, k=quad*8+j per kc)
  f16x8 qf[2][8];
#pragma unroll
  for (int sub = 0; sub < 2; ++sub) {
    const size_t qoff = (size_t)(grow + sub * 16 + l15) * 256 + quad * 8;
#pragma unroll
    for (int kc = 0; kc < 8; ++kc)
      qf[sub][kc] = *(const f16x8*)(Qh + qoff + kc * 32);
  }

  // staging: group g = b*256 + kz*64 + it; wave w stages frags 4w..4w+3 of K and V
  const char* kg[4];
  const char* vg[4];
#pragma unroll
  for (int i = 0; i < 4; ++i) {
    int f = 4 * w + i;
    kg[i] = Kf + (((size_t)(b * 256 + kz * 64)) * 8 + f) * 1024 + lane * 16;
    vg[i] = Vf + (((size_t)(b * 256 + kz * 64)) * 8 + f) * 1024 + lane * 16;
  }
  auto stage = [&](int buf) {
    char* base = &KVs[buf][0];
#pragma unroll
    for (int i = 0; i < 4; ++i) { gll16(kg[i], base + (4 * w + i) * 1024); kg[i] += 8192; }
#pragma unroll
    for (int i = 0; i < 4; ++i) { gll16(vg[i], base + 8192 + (4 * w + i) * 1024); vg[i] += 8192; }
  };

  f32x4 o0[16], o1[16];
#pragma unroll
  for (int ct = 0; ct < 16; ++ct) {
    o0[ct] = (f32x4){0.f, 0.f, 0.f, 0.f};
    o1[ct] = (f32x4){0.f, 0.f, 0.f, 0.f};
  }
  float m0 = -3.0e38f, m1 = -3.0e38f, l0 = 0.f, l1 = 0.f;

  stage(0);

  for (int it = 0; it < 64; ++it) {
    __syncthreads();
    if (it < 63) stage((it + 1) & 1);
    const char* Bf = &KVs[it & 1][0];

    // QK: S^T[key][q] for one 16-key tile, both q-subtiles
    f32x4 s0 = (f32x4){0.f,0.f,0.f,0.f};
    f32x4 s1 = (f32x4){0.f,0.f,0.f,0.f};
#pragma unroll
    for (int kc = 0; kc < 8; ++kc) {
      f16x8 kA = *(const f16x8*)(Bf + kc * 1024 + lane * 16);
      s0 = MFMAH(kA, qf[0][kc], s0);
      s1 = MFMAH(kA, qf[1][kc], s1);
    }

    // online softmax (lane: q=l15, keys quad*4+r)
    float mn0, mn1, al0, al1;
    f16x4 pah0, pah1;
    {
      float t = fmaxf(fmaxf(s0[0], s0[1]), fmaxf(s0[2], s0[3]));
      t = fmaxf(t, __shfl_xor(t, 16));
      t = fmaxf(t, __shfl_xor(t, 32));
      mn0 = fmaxf(m0, t);
      al0 = __expf(m0 - mn0);
      float p0 = __expf(s0[0] - mn0), p1 = __expf(s0[1] - mn0);
      float p2 = __expf(s0[2] - mn0), p3 = __expf(s0[3] - mn0);
      float ps = (p0 + p1) + (p2 + p3);
      ps += __shfl_xor(ps, 16);
      ps += __shfl_xor(ps, 32);
      l0 = l0 * al0 + ps;
      pah0[0] = (f16)p0; pah0[1] = (f16)p1; pah0[2] = (f16)p2; pah0[3] = (f16)p3;
    }
    {
      float t = fmaxf(fmaxf(s1[0], s1[1]), fmaxf(s1[2], s1[3]));
      t = fmaxf(t, __shfl_xor(t, 16));
      t = fmaxf(t, __shfl_xor(t, 32));
      mn1 = fmaxf(m1, t);
      al1 = __expf(m1 - mn1);
      float p0 = __expf(s1[0] - mn1), p1 = __expf(s1[1] - mn1);
      float p2 = __expf(s1[2] - mn1), p3 = __expf(s1[3] - mn1);
      float ps = (p0 + p1) + (p2 + p3);
      ps += __shfl_xor(ps, 16);
      ps += __shfl_xor(ps, 32);
      l1 = l1 * al1 + ps;
      pah1[0] = (f16)p0; pah1[1] = (f16)p1; pah1[2] = (f16)p2; pah1[3] = (f16)p3;
    }

    if (__any(mn0 > m0)) {
      float a0 = __shfl(al0, (quad << 2) + 0);
      float a1 = __shfl(al0, (quad << 2) + 1);
      float a2 = __shfl(al0, (quad << 2) + 2);
      float a3 = __shfl(al0, (quad << 2) + 3);
#pragma unroll
      for (int ct = 0; ct < 16; ++ct) {
        o0[ct][0] *= a0; o0[ct][1] *= a1; o0[ct][2] *= a2; o0[ct][3] *= a3;
      }
    }
    if (__any(mn1 > m1)) {
      float a0 = __shfl(al1, (quad << 2) + 0);
      float a1 = __shfl(al1, (quad << 2) + 1);
      float a2 = __shfl(al1, (quad << 2) + 2);
      float a3 = __shfl(al1, (quad << 2) + 3);
#pragma unroll
      for (int ct = 0; ct < 16; ++ct) {
        o1[ct][0] *= a0; o1[ct][1] *= a1; o1[ct][2] *= a2; o1[ct][3] *= a3;
      }
    }
    m0 = mn0;  m1 = mn1;

    // PV: O += P @ V (16 keys; V frag b64: n=dim=l15, k=key=quad*4+j)
#pragma unroll
    for (int ct = 0; ct < 16; ++ct) {
      f16x4 vf4 = *(const f16x4*)(Bf + 8192 + ct * 512 + lane * 8);
      o0[ct] = MFMAH16(pah0, vf4, o0[ct]);
      o1[ct] = MFMAH16(pah1, vf4, o1[ct]);
    }
  }

  // store fp16 partials + (m,l)
  f16* Od = Pp + (size_t)kz * NE;
#pragma unroll
  for (int r = 0; r < 4; ++r) {
    const size_t ro0 = (size_t)(grow + quad * 4 + r) * 256 + l15;
    const size_t ro1 = (size_t)(grow + 16 + quad * 4 + r) * 256 + l15;
#pragma unroll
    for (int ct = 0; ct < 16; ++ct) {
      Od[ro0 + ct * 16] = (f16)o0[ct][r];
      Od[ro1 + ct * 16] = (f16)o1[ct][r];
    }
  }
  if (lane < 16) {
    Mp[kz * NROWS + grow + l15] = m0;
    Lp[kz * NROWS + grow + l15] = l0;
    Mp[kz * NROWS + grow + 16 + l15] = m1;
    Lp[kz * NROWS + grow + 16 + l15] = l1;
  }
}

// ---------------------------------------------------------------------------
// Fused split-K merge + output projection. 512 blocks x 32 rows (r8-validated).
// ---------------------------------------------------------------------------
__global__ __launch_bounds__(256)
void oproj_mfma_kernel(const f16* __restrict__ Pp, const float* __restrict__ Mp,
                       const float* __restrict__ Lp, const f16* __restrict__ Wto,
                       const float* __restrict__ bo, float* __restrict__ out)
{
  __shared__ f16 xs[32][264];
  __shared__ __align__(16) char Bs[2][16384];
  const int tid = threadIdx.x, lane = tid & 63, w = tid >> 6;
  const int l15 = lane & 15, quad = lane >> 4;
  const int rb = blockIdx.x * 32;

  auto stageB = [&](int buf, int kc) {
    char* base = &Bs[buf][0];
#pragma unroll
    for (int i = 0; i < 4; ++i) {
      int ct = 4 * w + i;
      gll16(Wto + (ct * 16 + l15) * 256 + kc * 32 + quad * 8,
            base + ct * 1024 + lane * 16);
    }
  };
  stageB(0, 0);

  const int c4 = (tid & 63) * 4;
  const int rsub = tid >> 6;
#pragma unroll
  for (int e = 0; e < 8; ++e) {
    int rl = e * 4 + rsub;
    int row = rb + rl;
    float m[4], l[4];
#pragma unroll
    for (int z = 0; z < 4; ++z) {
      m[z] = Mp[z * NROWS + row];
      l[z] = Lp[z * NROWS + row];
    }
    float mm = fmaxf(fmaxf(m[0], m[1]), fmaxf(m[2], m[3]));
    float wz[4], denom = 0.f;
#pragma unroll
    for (int z = 0; z < 4; ++z) { wz[z] = __expf(m[z] - mm); denom += wz[z] * l[z]; }
    float inv = 1.0f / denom;
    float s0 = 0.f, s1 = 0.f, s2 = 0.f, s3 = 0.f;
#pragma unroll
    for (int z = 0; z < 4; ++z) {
      f16x4 h = *(const f16x4*)(Pp + (size_t)z * NE + (size_t)row * 256 + c4);
      s0 += wz[z] * (float)h[0];
      s1 += wz[z] * (float)h[1];
      s2 += wz[z] * (float)h[2];
      s3 += wz[z] * (float)h[3];
    }
    f16x4 xv;
    xv[0] = (f16)(s0 * inv); xv[1] = (f16)(s1 * inv);
    xv[2] = (f16)(s2 * inv); xv[3] = (f16)(s3 * inv);
    *(f16x4*)&xs[rl][c4] = xv;
  }

  const int rw = (w & 1) * 16;
  const int cg = (w >> 1) * 8;
  f32x4 acc[8];
#pragma unroll
  for (int c = 0; c < 8; ++c) acc[c] = (f32x4){0.f, 0.f, 0.f, 0.f};

  for (int kc = 0; kc < 8; ++kc) {
    __syncthreads();
    if (kc < 7) stageB((kc + 1) & 1, kc + 1);
    const char* Bb = &Bs[kc & 1][0];
    f16x8 a = *(const f16x8*)&xs[rw + l15][kc * 32 + quad * 8];
#pragma unroll
    for (int c = 0; c < 8; ++c) {
      f16x8 b = *(const f16x8*)(Bb + (cg + c) * 1024 + lane * 16);
      acc[c] = MFMAH(a, b, acc[c]);
    }
  }

#pragma unroll
  for (int c = 0; c < 8; ++c) {
    int col = (cg + c) * 16 + l15;
    float bct = bo[col];
#pragma unroll
    for (int r = 0; r < 4; ++r)
      out[(size_t)(rb + rw + quad * 4 + r) * 256 + col] = acc[c][r] + bct;
  }
}

// ---------------------------------------------------------------------------
extern "C" void kernel_launch(void* const* d_in, const int* in_sizes, int n_in,
                              void* d_out, int out_size, void* d_ws, size_t ws_size,
                              hipStream_t stream)
{
  const float* inp = (const float*)d_in[0];
  const float* wq  = (const float*)d_in[1];
  const float* bq  = (const float*)d_in[2];
  const float* wk  = (const float*)d_in[3];
  const float* bk  = (const float*)d_in[4];
  const float* wv  = (const float*)d_in[5];
  const float* bv  = (const float*)d_in[6];
  const float* wo  = (const float*)d_in[7];
  const float* bo  = (const float*)d_in[8];
  float* out = (float*)d_out;

  // ws (~60 MB): Qh, Kf, Vf (NE f16), Wt (4*65536 f16), Pp (4*NE f16), m/l
  f16* Qh = (f16*)d_ws;
  f16* Kf = Qh + NE;
  f16* Vf = Kf + NE;
  f16* Wt = Vf + NE;
  f16* Pp = Wt + 4 * 65536;
  float* Mp = (float*)(Pp + 4 * NE);
  float* Lp = Mp + 4 * NROWS;

  prep_wt_kernel<<<dim3(256, 4), 256, 0, stream>>>(wq, wk, wv, wo, Wt);

  qkv_mfma_kernel<<<dim3(256, 3), 256, 0, stream>>>(
      inp, Wt, bq, bk, bv, Qh, Kf, Vf);

  attn9_kernel<<<1024, 128, 0, stream>>>(Qh, (const char*)Kf, (const char*)Vf,
                                         Pp, Mp, Lp);

  oproj_mfma_kernel<<<512, 256, 0, stream>>>(Pp, Mp, Lp, Wt + 3 * 65536, bo, out);
}